// Round 4
// baseline (538.904 us; speedup 1.0000x reference)
//
#include <hip/hip_runtime.h>
#include <stdint.h>

#define N_K   10000
#define CIN   3
#define SEQ   1000
#define KM    11
#define NCLS  1024   // class key = (d-1)*4 + padbits ; d <= 166 -> key < 668
#define MAXQ  3400   // >= 10000/4 + NCLS

typedef _Float16 h2 __attribute__((ext_vector_type(2)));

// ---- workspace layout (int units) ------------------------------------------
// [0..15] per-batch queue counters, [16] NOCT
#define WS_QUADS_OFF   64
#define WS_SORT_OFF    (WS_QUADS_OFF + 2*(MAXQ+2))
#define WS_QDIL_OFF    (WS_SORT_OFF + N_K)
#define WS_QSPAN_OFF   (WS_QDIL_OFF + MAXQ + 4)
#define WS_QMETA_OFF   (WS_QSPAN_OFF + 2*(MAXQ+2))  // int4-aligned (checked)
#define WS_QBIAS_OFF   (WS_QMETA_OFF + 4*(MAXQ+2))
#define WS_QJ_OFF      (WS_QBIAS_OFF + 4*(MAXQ+2))
#define WS_QW_OFF      (WS_QJ_OFF + 4*(MAXQ+2))     // 17 uint4 per quad

// ---------------- prep: class-sort, quad build, weight pre-pack --------------
__global__ __launch_bounds__(1024) void prep_kernel(
    const float* __restrict__ w, const float* __restrict__ bias,
    const int* __restrict__ dil, const int* __restrict__ start,
    const int* __restrict__ out_len, const int* __restrict__ pad_max_p,
    int* __restrict__ ws) {
  __shared__ int sA[NCLS];
  __shared__ int sB[NCLS];
  const int tid = threadIdx.x;
  const int pm = pad_max_p[0];

  int2* quads   = (int2*)(ws + WS_QUADS_OFF);
  int*  sortedj = ws + WS_SORT_OFF;
  int*  qdil    = ws + WS_QDIL_OFF;
  int2* qspan   = (int2*)(ws + WS_QSPAN_OFF);
  int4* qmeta   = (int4*)(ws + WS_QMETA_OFF);
  float4* qbias = (float4*)(ws + WS_QBIAS_OFF);
  int4* qjv     = (int4*)(ws + WS_QJ_OFF);
  unsigned* qw  = (unsigned*)(ws + WS_QW_OFF);

  // 1. class histogram
  sA[tid] = 0;
  __syncthreads();
  for (int j = tid; j < N_K; j += 1024) {
    int d = dil[j];
    int pads = pm - start[j];
    int key = (d - 1) * 4 + (pads > 0 ? 2 : 0) + (2 * pads > 7 * d ? 1 : 0);
    atomicAdd(&sA[min(key, NCLS - 1)], 1);
  }
  __syncthreads();
  // 2. inclusive scan of sA (Hillis-Steele, hazard-free)
  for (int off = 1; off < NCLS; off <<= 1) {
    int v = (tid >= off) ? sA[tid - off] : 0;
    __syncthreads();
    sA[tid] += v;
    __syncthreads();
  }
  sB[tid] = tid ? sA[tid - 1] : 0;  // exclusive
  __syncthreads();
  // 3. scatter j -> sortedj (class-grouped)
  for (int j = tid; j < N_K; j += 1024) {
    int d = dil[j];
    int pads = pm - start[j];
    int key = (d - 1) * 4 + (pads > 0 ? 2 : 0) + (2 * pads > 7 * d ? 1 : 0);
    int pos = atomicAdd(&sB[min(key, NCLS - 1)], 1);
    sortedj[pos] = j;
  }
  __syncthreads();
  // 4. per-class quad counts -> scan -> emit quads in class order
  const int n_c = sA[tid] - (tid ? sA[tid - 1] : 0);
  const int cstart = sA[tid] - n_c;
  const int nq_c = (n_c + 3) >> 2;
  sB[tid] = nq_c;
  __syncthreads();
  for (int off = 1; off < NCLS; off <<= 1) {
    int v = (tid >= off) ? sB[tid - off] : 0;
    __syncthreads();
    sB[tid] += v;
    __syncthreads();
  }
  const int qstart = sB[tid] - nq_c;
  for (int u = 0; u < nq_c; ++u)
    quads[qstart + u] = make_int2(cstart + 4 * u, cstart + n_c - 1);
  __syncthreads();
  const int Qtot = sB[NCLS - 1];
  if (tid == 0) {
    quads[Qtot] = quads[Qtot > 0 ? Qtot - 1 : 0];  // octet pad
    ws[16] = (Qtot + 1) >> 1;                      // NOCT
    for (int i = 0; i < 16; ++i) ws[i] = 0;        // queue counters
  }
  __syncthreads();
  // 5. pack per-quad data (members, span, meta, bias, fp16 weights)
  for (int q = tid; q <= Qtot; q += 1024) {
    int2 qr = quads[q];
    int jm[4];
#pragma unroll
    for (int m = 0; m < 4; ++m) jm[m] = sortedj[min(qr.x + m, qr.y)];
    qdil[q] = dil[jm[0]];
    int tlo = 0x7fffffff, thi = 0;
    int4 meta; float4 bv; int4 jv;
    int* mp = (int*)&meta; float* bp = (float*)&bv; int* jp = (int*)&jv;
#pragma unroll
    for (int m = 0; m < 4; ++m) {
      int smv = start[jm[m]];
      int ol = out_len[jm[m]];
      tlo = min(tlo, smv);
      thi = max(thi, smv + ol);
      mp[m] = (smv << 16) | ol;
      bp[m] = bias[jm[m]];
      jp[m] = jm[m];
    }
    qspan[q] = make_int2(tlo, thi);
    qmeta[q] = meta;
    qbias[q] = bv;
    qjv[q] = jv;
    unsigned* qq = qw + (size_t)q * 68;
#pragma unroll
    for (int m = 0; m < 4; ++m) {
      const float* wj = w + (size_t)jm[m] * (CIN * KM);
#pragma unroll
      for (int k = 0; k < KM; ++k) {
        h2 a;
        a.x = (_Float16)wj[k];
        a.y = (_Float16)wj[KM + k];
        qq[m * KM + k] = __builtin_bit_cast(unsigned, a);
      }
    }
#pragma unroll
    for (int p = 0; p < 2; ++p) {
      const float* w0 = w + (size_t)jm[2 * p] * (CIN * KM) + 2 * KM;
      const float* w1 = w + (size_t)jm[2 * p + 1] * (CIN * KM) + 2 * KM;
#pragma unroll
      for (int k = 0; k < KM; ++k) {
        h2 a;
        a.x = (_Float16)w0[k];
        a.y = (_Float16)w1[k];
        qq[44 + p * KM + k] = __builtin_bit_cast(unsigned, a);
      }
    }
  }
}

// ---------------- main: persistent blocks, per-batch work queues -------------
// block = 4 waves; wave <-> one batch; wave = 2 kernel-subsets x 32 tau-lanes.
// Per tap a wave reads 2 runs of 32 consecutive u64 -> bank-uniform LDS.
__global__ __launch_bounds__(256, 4) void rocket_kernel(
    const float* __restrict__ x, const int* __restrict__ pad_max_p,
    int* __restrict__ ws, float* __restrict__ out) {
  __shared__ __align__(16) unsigned long long xs[4 * 1002];

  const int tid = threadIdx.x;
  const int wv = tid >> 6;
  const int lane = tid & 63;
  const int sub = lane >> 5;
  const int s = lane & 31;
  const int bg = blockIdx.x & 3;
  const int b = bg * 4 + wv;

  // stage 4 batches, packed (c0,c1|c2,0) fp16 per position; sentinels 0/1001
  for (int lbb = 0; lbb < 4; ++lbb) {
    const float* xb = x + (size_t)(bg * 4 + lbb) * (CIN * SEQ);
    for (int pos = tid; pos < SEQ; pos += 256) {
      float a0 = xb[pos];
      float a1 = xb[SEQ + pos];
      float a2 = xb[2 * SEQ + pos];
      unsigned u0 = (unsigned)__builtin_bit_cast(unsigned short, (_Float16)a0);
      unsigned u1 = (unsigned)__builtin_bit_cast(unsigned short, (_Float16)a1);
      unsigned u2 = (unsigned)__builtin_bit_cast(unsigned short, (_Float16)a2);
      xs[lbb * 1002 + 1 + pos] =
          (unsigned long long)(u0 | (u1 << 16)) | ((unsigned long long)u2 << 32);
    }
  }
  if (tid < 8) xs[(tid >> 1) * 1002 + (tid & 1) * 1001] = 0ULL;
  __syncthreads();

  const int pm = pad_max_p[0];
  const int NOCT = ws[16];
  int* ctr = ws;
  const int* qdil = ws + WS_QDIL_OFF;
  const int2* qspan = (const int2*)(ws + WS_QSPAN_OFF);
  const int4* qmeta = (const int4*)(ws + WS_QMETA_OFF);
  const float4* qbias = (const float4*)(ws + WS_QBIAS_OFF);
  const int4* qjv = (const int4*)(ws + WS_QJ_OFF);
  const uint4* qw = (const uint4*)(ws + WS_QW_OFF);

  const unsigned long long* xbase = xs + wv * 1002;

  for (;;) {
    int o = 0;
    if (lane == 0) o = atomicAdd(&ctr[b], 1);
    o = __shfl(o, 0);
    if (o >= NOCT) break;
    const int q = 2 * o + sub;

    const int4 meta = qmeta[q];
    const float4 bv = qbias[q];
    const int4 jv = qjv[q];
    const int d = qdil[q];
    const int2 span = qspan[q];

    h2 W[68];
    {
      const uint4* wp = qw + (size_t)q * 17;
#pragma unroll
      for (int i = 0; i < 17; ++i) {
        uint4 u = wp[i];
        W[4 * i + 0] = __builtin_bit_cast(h2, u.x);
        W[4 * i + 1] = __builtin_bit_cast(h2, u.y);
        W[4 * i + 2] = __builtin_bit_cast(h2, u.z);
        W[4 * i + 3] = __builtin_bit_cast(h2, u.w);
      }
    }
    int sm[4], olm[4];
    float bb[4];
    {
      const int* mp = (const int*)&meta;
      const float* bp = (const float*)&bv;
#pragma unroll
      for (int m = 0; m < 4; ++m) {
        sm[m] = mp[m] >> 16;
        olm[m] = mp[m] & 0xffff;
        bb[m] = bp[m];
      }
    }
    int kd[KM];
#pragma unroll
    for (int k = 0; k < KM; ++k) kd[k] = k * d;
    const int iA = pm - 1;
    const int iB = 1000 + pm - 10 * d;

    const int nIter = (span.y - span.x + 31) >> 5;
    int t = span.x + s;
    int pb = 1 + t - pm;  // slot index for tap 0 (slot = 1 + position)

    float mx[4] = {-3.0e38f, -3.0e38f, -3.0e38f, -3.0e38f};
    int cnt[4] = {0, 0, 0, 0};

#pragma unroll 1
    for (int i = 0; i < nIter; ++i) {
      float a0[4] = {bb[0], bb[1], bb[2], bb[3]};
      float a1[4] = {0.f, 0.f, 0.f, 0.f};
      if (t >= iA && t <= iB) {
        // interior: all 11 slots provably in [0,1001], no clamp
#pragma unroll
        for (int k = 0; k < KM; ++k) {
          unsigned long long v = xbase[pb + kd[k]];
          unsigned lo32 = (unsigned)v;
          unsigned hi32 = (unsigned)(v >> 32);
          h2 xl = __builtin_bit_cast(h2, lo32);
          h2 xhl = __builtin_bit_cast(h2, hi32);
          h2 xhh = __builtin_bit_cast(h2, hi32 << 16);
          a0[0] = __builtin_amdgcn_fdot2(xl, W[0 * KM + k], a0[0], false);
          a0[1] = __builtin_amdgcn_fdot2(xl, W[1 * KM + k], a0[1], false);
          a0[2] = __builtin_amdgcn_fdot2(xl, W[2 * KM + k], a0[2], false);
          a0[3] = __builtin_amdgcn_fdot2(xl, W[3 * KM + k], a0[3], false);
          a1[0] = __builtin_amdgcn_fdot2(xhl, W[44 + k], a1[0], false);
          a1[1] = __builtin_amdgcn_fdot2(xhh, W[44 + k], a1[1], false);
          a1[2] = __builtin_amdgcn_fdot2(xhl, W[55 + k], a1[2], false);
          a1[3] = __builtin_amdgcn_fdot2(xhh, W[55 + k], a1[3], false);
        }
      } else {
        // edge: clamp into sentinel zeros at slots 0 / 1001
#pragma unroll
        for (int k = 0; k < KM; ++k) {
          int qq = min(max(pb + kd[k], 0), 1001);
          unsigned long long v = xbase[qq];
          unsigned lo32 = (unsigned)v;
          unsigned hi32 = (unsigned)(v >> 32);
          h2 xl = __builtin_bit_cast(h2, lo32);
          h2 xhl = __builtin_bit_cast(h2, hi32);
          h2 xhh = __builtin_bit_cast(h2, hi32 << 16);
          a0[0] = __builtin_amdgcn_fdot2(xl, W[0 * KM + k], a0[0], false);
          a0[1] = __builtin_amdgcn_fdot2(xl, W[1 * KM + k], a0[1], false);
          a0[2] = __builtin_amdgcn_fdot2(xl, W[2 * KM + k], a0[2], false);
          a0[3] = __builtin_amdgcn_fdot2(xl, W[3 * KM + k], a0[3], false);
          a1[0] = __builtin_amdgcn_fdot2(xhl, W[44 + k], a1[0], false);
          a1[1] = __builtin_amdgcn_fdot2(xhh, W[44 + k], a1[1], false);
          a1[2] = __builtin_amdgcn_fdot2(xhl, W[55 + k], a1[2], false);
          a1[3] = __builtin_amdgcn_fdot2(xhh, W[55 + k], a1[3], false);
        }
      }
#pragma unroll
      for (int m = 0; m < 4; ++m) {
        float val = a0[m] + a1[m];
        bool in = (unsigned)(t - sm[m]) < (unsigned)olm[m];
        mx[m] = fmaxf(mx[m], in ? val : -3.0e38f);
        cnt[m] += (in && val > 0.f) ? 1 : 0;
      }
      t += 32;
      pb += 32;
    }

    // reduce across the 32 tau-lanes of this subset
#pragma unroll
    for (int m = 0; m < 4; ++m) {
#pragma unroll
      for (int off = 1; off < 32; off <<= 1) {
        mx[m] = fmaxf(mx[m], __shfl_xor(mx[m], off));
        cnt[m] += __shfl_xor(cnt[m], off);
      }
    }
    if (s == 0) {
      const int* jp = (const int*)&jv;
#pragma unroll
      for (int m = 0; m < 4; ++m) {
        float2 r;
        r.x = mx[m];
        r.y = (float)cnt[m] / (float)olm[m];
        *(float2*)(out + (size_t)b * (2 * N_K) + 2 * jp[m]) = r;
      }
    }
  }
}

extern "C" void kernel_launch(void* const* d_in, const int* in_sizes, int n_in,
                              void* d_out, int out_size, void* d_ws, size_t ws_size,
                              hipStream_t stream) {
  const float* x       = (const float*)d_in[0];
  const float* weight  = (const float*)d_in[1];
  const float* bias    = (const float*)d_in[2];
  const int*   dil     = (const int*)d_in[3];
  const int*   start   = (const int*)d_in[4];
  const int*   out_len = (const int*)d_in[5];
  const int*   pad_max = (const int*)d_in[6];
  (void)in_sizes; (void)n_in; (void)out_size; (void)ws_size;

  int* ws = (int*)d_ws;

  prep_kernel<<<1, 1024, 0, stream>>>(weight, bias, dil, start, out_len,
                                      pad_max, ws);

  rocket_kernel<<<1024, 256, 0, stream>>>(x, pad_max, ws, (float*)d_out);
}